// Round 13
// baseline (723.852 us; speedup 1.0000x reference)
//
#include <hip/hip_runtime.h>
#include <cfloat>

// Problem constants (match reference setup_inputs)
#define Nn 50000
#define Ee 800000
#define Etot (Ee + Nn)   // edges + self loops = 850000
#define Gg 64
#define HIDc 256
#define BN_EPS 1e-5f

typedef unsigned int   uint32;
typedef unsigned short ushort16;
typedef short  bf16x8 __attribute__((ext_vector_type(8)));
typedef float  f32x4  __attribute__((ext_vector_type(4)));

// ---------------------------------------------------------------------------
// helpers
// ---------------------------------------------------------------------------
__device__ inline ushort16 f2bf(float f) {            // RNE fp32 -> bf16
    uint32 u = __float_as_uint(f);
    u = (u + 0x7fffu + ((u >> 16) & 1u)) >> 16;
    return (ushort16)u;
}
__device__ inline uint32 pack2(float a, float b) {
    return (uint32)f2bf(a) | ((uint32)f2bf(b) << 16);
}
// monotone float<->uint encoding for atomicMax-based float max
__device__ inline uint32 fenc(float f) {
    uint32 b = __float_as_uint(f);
    return (b & 0x80000000u) ? ~b : (b | 0x80000000u);
}
__device__ inline float fdec(uint32 u) {
    uint32 b = (u & 0x80000000u) ? (u & 0x7fffffffu) : ~u;
    return __uint_as_float(b);
}

// W swizzle to MFMA A-operand fragment order:
// WS[((cb*KB + kb)*64 + q*16 + m)*8 + e]  where cb=c>>4, m=c&15,
// kb=k>>5, q=(k>>3)&3, e=k&7.  A wave then reads 64 lanes x 16B contiguous.
__device__ inline long ws_index(int c, int k, int KB) {
    int cb = c >> 4, m = c & 15, kb = k >> 5, q = (k >> 3) & 3, e = k & 7;
    return (((long)(cb * KB + kb) * 64 + q * 16 + m) << 3) + e;
}

// ---------------------------------------------------------------------------
// prep kernel: ea_sum | M | W swizzles | x->bf16 | hist   (one dispatch)
// ---------------------------------------------------------------------------
#define CVT4 (Nn * 128 / 4)
#define CVT_BLKS ((CVT4 + 255) / 256)
#define EBKS ((Etot + 255) / 256)
__global__ __launch_bounds__(256) void prep_kernel(
        const float* __restrict__ ea, float* __restrict__ ea_s,
        const float* __restrict__ We0, const float* __restrict__ ae0,
        const float* __restrict__ We1, const float* __restrict__ ae1,
        const float* __restrict__ We2, const float* __restrict__ ae2,
        float* __restrict__ M,
        const float* __restrict__ W0, const float* __restrict__ Wskip,
        const float* __restrict__ W1, const float* __restrict__ W2,
        ushort16* __restrict__ WtC, ushort16* __restrict__ Wt1,
        ushort16* __restrict__ Wt2,
        const float* __restrict__ x, ushort16* __restrict__ xbf,
        const int* __restrict__ ei, int* __restrict__ counts) {
    int bid = blockIdx.x, t = threadIdx.x;
    if (bid < 256) {
        __shared__ float sh0[256], sh1[256];
        float s0 = 0.f, s1 = 0.f;
        for (int e = bid * 256 + t; e < Ee; e += 256 * 256) {
            s0 += ea[2 * e];
            s1 += ea[2 * e + 1];
        }
        sh0[t] = s0; sh1[t] = s1;
        __syncthreads();
        for (int off = 128; off > 0; off >>= 1) {
            if (t < off) { sh0[t] += sh0[t + off]; sh1[t] += sh1[t + off]; }
            __syncthreads();
        }
        if (t == 0) { atomicAdd(&ea_s[0], sh0[0]); atomicAdd(&ea_s[1], sh1[0]); }
    } else if (bid == 256) {
        if (t >= 18) return;
        int l = t < 8 ? 0 : (t < 16 ? 1 : 2);
        int r = t - l * 8;
        const float* We = (l == 0) ? We0 : (l == 1 ? We1 : We2);
        const float* ae = (l == 0) ? ae0 : (l == 1 ? ae1 : ae2);
        int Hl = (l < 2) ? 4 : 1;
        int Cl = 256 / Hl;
        int d = r / Hl, hh = r % Hl;
        float s = 0.f;
        for (int c = 0; c < Cl; ++c)
            s += We[d * 256 + hh * Cl + c] * ae[hh * Cl + c];
        M[l * 8 + r] = s;
    } else if (bid < 385) {          // W0: cols 0..255, K=128 (KB=4)
        int k = bid - 257;
        WtC[ws_index(t, k, 4)] = f2bf(W0[(long)k * 256 + t]);
    } else if (bid < 513) {          // Wskip: cols 256..511, K=128
        int k = bid - 385;
        WtC[ws_index(256 + t, k, 4)] = f2bf(Wskip[(long)k * 256 + t]);
    } else if (bid < 769) {          // W1: K=256 (KB=8)
        int k = bid - 513;
        Wt1[ws_index(t, k, 8)] = f2bf(W1[(long)k * 256 + t]);
    } else if (bid < 1025) {         // W2
        int k = bid - 769;
        Wt2[ws_index(t, k, 8)] = f2bf(W2[(long)k * 256 + t]);
    } else if (bid < 1025 + CVT_BLKS) {
        int i = (bid - 1025) * 256 + t;
        if (i < CVT4) {
            float4 v = *(const float4*)&x[i * 4];
            ushort4 o;
            o.x = f2bf(v.x); o.y = f2bf(v.y); o.z = f2bf(v.z); o.w = f2bf(v.w);
            *(ushort4*)&xbf[i * 4] = o;
        }
    } else {                         // histogram
        int e = (bid - 1025 - CVT_BLKS) * 256 + t;
        if (e < Etot) {
            int d = (e < Ee) ? ei[Ee + e] : (e - Ee);
            atomicAdd(&counts[d], 1);
        }
    }
}

// ---------------------------------------------------------------------------
// CSR build: scan1 -> scan23 -> scatter
// ---------------------------------------------------------------------------
__global__ void scan1_kernel(const int* __restrict__ in, int* __restrict__ inc,
                             int* __restrict__ bsums) {
    __shared__ int sh[256];
    int i = blockIdx.x * 256 + threadIdx.x;
    int v = (i < Nn) ? in[i] : 0;
    sh[threadIdx.x] = v;
    __syncthreads();
    for (int off = 1; off < 256; off <<= 1) {
        int t = ((int)threadIdx.x >= off) ? sh[threadIdx.x - off] : 0;
        __syncthreads();
        sh[threadIdx.x] += t;
        __syncthreads();
    }
    if (i < Nn) inc[i] = sh[threadIdx.x];
    if (threadIdx.x == 255) bsums[blockIdx.x] = sh[255];
}

__global__ void scan23_kernel(const int* __restrict__ inc, const int* __restrict__ bsums,
                              int* __restrict__ row_start, int* __restrict__ cursor, int nb) {
    __shared__ int sh[256];
    int b = blockIdx.x, t = threadIdx.x;
    sh[t] = (t < b && t < nb) ? bsums[t] : 0;
    __syncthreads();
    for (int off = 128; off > 0; off >>= 1) {
        if (t < off) sh[t] += sh[t + off];
        __syncthreads();
    }
    int base = sh[0];
    int i = b * 256 + t;
    if (i < Nn) {
        int v = inc[i] + base;
        row_start[i + 1] = v;
        cursor[i + 1] = v;
    }
    if (i == 0) { row_start[0] = 0; cursor[0] = 0; }
}

__global__ void scatter_kernel(const int* __restrict__ ei, const float* __restrict__ ea,
                               const float* __restrict__ ea_sum, int* __restrict__ cursor,
                               int* __restrict__ src_sorted, float* __restrict__ ea_sorted) {
    int e = blockIdx.x * blockDim.x + threadIdx.x;
    if (e >= Etot) return;
    int s, d; float e0, e1;
    if (e < Ee) {
        s = ei[e]; d = ei[Ee + e];
        e0 = ea[2 * e]; e1 = ea[2 * e + 1];
    } else {
        s = d = e - Ee;
        const float invE = 1.f / (float)Ee;
        e0 = ea_sum[0] * invE; e1 = ea_sum[1] * invE;
    }
    int pos = atomicAdd(&cursor[d], 1);
    src_sorted[pos] = s;
    ea_sorted[2 * pos]     = e0;
    ea_sorted[2 * pos + 1] = e1;
}

// ---------------------------------------------------------------------------
// Barrier-free MFMA bf16 GEMM: BOTH operands read directly from global.
// B from fragment-swizzled WS (L2-resident); A per-lane dwordx4 in fragment
// pattern (16 rows x 64B fully consumed per wave; L2-served, 2x wc overlap).
// No LDS, no __syncthreads. KB templated (4 or 8) for full unroll.
// Fused attention dots into ssrc/sdst[row*4+part].
// If outS != null: grid.y=4, col blocks 256..511 route to outS (+bskip).
// ---------------------------------------------------------------------------
template <int KB>
__global__ __launch_bounds__(256) void mfma_gemm_kernel(
        const ushort16* __restrict__ A,   // [n][K] bf16
        const ushort16* __restrict__ WS,  // swizzled weights
        uint32* __restrict__ outF,        // feature out [n][128] packed bf16x2
        uint32* __restrict__ outS,        // skip out (or null)
        const float* __restrict__ bskip,
        const float* __restrict__ a_s, const float* __restrict__ a_d,
        float* __restrict__ ssrc, float* __restrict__ sdst, int n) {
    const int K = KB * 32;
    const int t    = threadIdx.x;
    const int row0 = blockIdx.x * 128;
    const int c0   = blockIdx.y * 128;
    const bool isSkip = (outS != nullptr) && (c0 >= 256);
    const int cc0  = isSkip ? c0 - 256 : c0;
    const int wave = t >> 6, lane = t & 63;
    const int wr = wave >> 1, wc = wave & 1;
    const int l15 = lane & 15, quad = lane >> 4;

    f32x4 acc[4][4];   // acc[j][i]: j = feature-col block, i = node-row block
#pragma unroll
    for (int j = 0; j < 4; ++j)
#pragma unroll
        for (int i = 0; i < 4; ++i) {
            acc[j][i][0] = 0.f; acc[j][i][1] = 0.f;
            acc[j][i][2] = 0.f; acc[j][i][3] = 0.f;
        }

    // per-frag A base (row clamped; clamped rows' results are never stored)
    long abase[4];
#pragma unroll
    for (int i = 0; i < 4; ++i) {
        int row = row0 + wr * 64 + i * 16 + l15;
        if (row >= n) row = n - 1;
        abase[i] = (long)row * K + quad * 8;
    }
    const ushort16* wsb = WS + (((long)((c0 + wc * 64) >> 4) * KB) << 9); // cb0*KB*512

#pragma unroll
    for (int kb = 0; kb < KB; ++kb) {
        bf16x8 af[4], bfv[4];
#pragma unroll
        for (int i = 0; i < 4; ++i)
            af[i] = *(const bf16x8*)&A[abase[i] + kb * 32];
#pragma unroll
        for (int j = 0; j < 4; ++j)
            bfv[j] = *(const bf16x8*)&wsb[((((long)j * KB + kb) * 64 + lane) << 3)];
#pragma unroll
        for (int j = 0; j < 4; ++j)
#pragma unroll
            for (int i = 0; i < 4; ++i)
                acc[j][i] = __builtin_amdgcn_mfma_f32_16x16x32_bf16(
                    bfv[j], af[i], acc[j][i], 0, 0, 0);
    }

    float4 bb[4];
#pragma unroll
    for (int j = 0; j < 4; ++j) {
        if (isSkip) bb[j] = *(const float4*)&bskip[cc0 + wc * 64 + j * 16 + quad * 4];
        else        bb[j] = make_float4(0.f, 0.f, 0.f, 0.f);
    }

    uint32* tgt = isSkip ? outS : outF;
#pragma unroll
    for (int i = 0; i < 4; ++i) {
        int row = row0 + wr * 64 + i * 16 + l15;
        if (row >= n) continue;
#pragma unroll
        for (int j = 0; j < 4; ++j) {
            int col = cc0 + wc * 64 + j * 16 + quad * 4;
            uint2 pk;
            pk.x = pack2(acc[j][i][0] + bb[j].x, acc[j][i][1] + bb[j].y);
            pk.y = pack2(acc[j][i][2] + bb[j].z, acc[j][i][3] + bb[j].w);
            *(uint2*)&tgt[(long)row * 128 + (col >> 1)] = pk;
        }
    }

    if (!isSkip && a_s != nullptr) {
        float4 asv[4], adv[4];
#pragma unroll
        for (int j = 0; j < 4; ++j) {
            int col = cc0 + wc * 64 + j * 16 + quad * 4;
            asv[j] = *(const float4*)&a_s[col];
            adv[j] = *(const float4*)&a_d[col];
        }
        const int part = (cc0 + wc * 64) >> 6;
#pragma unroll
        for (int i = 0; i < 4; ++i) {
            float ps = 0.f, pd = 0.f;
#pragma unroll
            for (int j = 0; j < 4; ++j) {
                ps += acc[j][i][0] * asv[j].x + acc[j][i][1] * asv[j].y
                    + acc[j][i][2] * asv[j].z + acc[j][i][3] * asv[j].w;
                pd += acc[j][i][0] * adv[j].x + acc[j][i][1] * adv[j].y
                    + acc[j][i][2] * adv[j].z + acc[j][i][3] * adv[j].w;
            }
            ps += __shfl_xor(ps, 16); ps += __shfl_xor(ps, 32);
            pd += __shfl_xor(pd, 16); pd += __shfl_xor(pd, 32);
            if (quad == 0) {
                int row = row0 + wr * 64 + i * 16 + l15;
                if (row < n) {
                    ssrc[row * 4 + part] = ps;
                    sdst[row * 4 + part] = pd;
                }
            }
        }
    }
}

// ---------------------------------------------------------------------------
// fused edge logits + segment softmax, one wave per dst node, CSR order.
// Single-pass: logits cached in registers (deg<=256), one write of w.
// H==1 sums the 4 partial slots of ssrc/sdst.
// ---------------------------------------------------------------------------
template <int H>
__global__ __launch_bounds__(256) void edge_softmax_kernel(
        const int* __restrict__ src_sorted, const int* __restrict__ row_start,
        const float* __restrict__ ea_sorted, const float* __restrict__ ssrc,
        const float* __restrict__ sdst, const float* __restrict__ M,
        float* __restrict__ w) {
    int node = (blockIdx.x * blockDim.x + threadIdx.x) >> 6;
    int lane = threadIdx.x & 63;
    if (node >= Nn) return;
    int beg = row_start[node], end = row_start[node + 1];
    int deg = end - beg;
    float sd[H], M0[H], M1[H], m[H], den[H];
    if (H == 4) {
#pragma unroll
        for (int h = 0; h < H; ++h) sd[h] = sdst[node * 4 + h];
    } else {
        float4 v = *(const float4*)&sdst[node * 4];
        sd[0] = v.x + v.y + v.z + v.w;
    }
#pragma unroll
    for (int h = 0; h < H; ++h) {
        M0[h] = M[h]; M1[h] = M[H + h];
        m[h] = -FLT_MAX; den[h] = 0.f;
    }
    auto ssval = [&](int s, int h) -> float {
        if (H == 4) return ssrc[s * 4 + h];
        float4 v = *(const float4*)&ssrc[s * 4];
        return v.x + v.y + v.z + v.w;
    };
    if (deg <= 256) {
        float lreg[4][H];
#pragma unroll
        for (int k = 0; k < 4; ++k) {
            int idx = beg + lane + (k << 6);
            if (idx < end) {
                int s = src_sorted[idx];
                float e0 = ea_sorted[2 * idx], e1 = ea_sorted[2 * idx + 1];
#pragma unroll
                for (int h = 0; h < H; ++h) {
                    float l = ssval(s, h) + sd[h] + e0 * M0[h] + e1 * M1[h];
                    l = (l > 0.f) ? l : 0.2f * l;
                    lreg[k][h] = l;
                    if (l > m[h]) { den[h] = den[h] * __expf(m[h] - l) + 1.f; m[h] = l; }
                    else den[h] += __expf(l - m[h]);
                }
            }
        }
#pragma unroll
        for (int h = 0; h < H; ++h) {
            for (int off = 32; off > 0; off >>= 1) {
                float om = __shfl_down(m[h], off);
                float od = __shfl_down(den[h], off);
                float nm = fmaxf(m[h], om);
                den[h] = den[h] * __expf(m[h] - nm) + od * __expf(om - nm);
                m[h] = nm;
            }
            m[h]   = __shfl(m[h], 0);
            den[h] = __shfl(den[h], 0);
            den[h] = 1.f / (den[h] + 1e-16f);
        }
#pragma unroll
        for (int k = 0; k < 4; ++k) {
            int idx = beg + lane + (k << 6);
            if (idx < end) {
#pragma unroll
                for (int h = 0; h < H; ++h)
                    w[(long)idx * H + h] = __expf(lreg[k][h] - m[h]) * den[h];
            }
        }
    } else {
        // 2-pass fallback
        for (int idx = beg + lane; idx < end; idx += 64) {
            int s = src_sorted[idx];
            float e0 = ea_sorted[2 * idx], e1 = ea_sorted[2 * idx + 1];
#pragma unroll
            for (int h = 0; h < H; ++h) {
                float l = ssval(s, h) + sd[h] + e0 * M0[h] + e1 * M1[h];
                l = (l > 0.f) ? l : 0.2f * l;
                w[(long)idx * H + h] = l;
                if (l > m[h]) { den[h] = den[h] * __expf(m[h] - l) + 1.f; m[h] = l; }
                else den[h] += __expf(l - m[h]);
            }
        }
#pragma unroll
        for (int h = 0; h < H; ++h) {
            for (int off = 32; off > 0; off >>= 1) {
                float om = __shfl_down(m[h], off);
                float od = __shfl_down(den[h], off);
                float nm = fmaxf(m[h], om);
                den[h] = den[h] * __expf(m[h] - nm) + od * __expf(om - nm);
                m[h] = nm;
            }
            m[h]   = __shfl(m[h], 0);
            den[h] = __shfl(den[h], 0);
            den[h] = 1.f / (den[h] + 1e-16f);
        }
        for (int idx = beg + lane; idx < end; idx += 64) {
#pragma unroll
            for (int h = 0; h < H; ++h) {
                float l = w[(long)idx * H + h];
                w[(long)idx * H + h] = __expf(l - m[h]) * den[h];
            }
        }
    }
}

// ---------------------------------------------------------------------------
// weighted gather (bf16 features) + bconv + BN + ELU + residual(bf16).
// 128 threads/node; thread c2 handles channels 2c2,2c2+1 (packed bf16x2).
// ---------------------------------------------------------------------------
__global__ __launch_bounds__(128) void agg_kernel(
        const int* __restrict__ src_sorted, const int* __restrict__ row_start,
        const uint32* __restrict__ hbuf2, const float* __restrict__ w,
        const float* __restrict__ bconv,
        const float* __restrict__ bn_g, const float* __restrict__ bn_b,
        const float* __restrict__ bn_m, const float* __restrict__ bn_v,
        const uint32* __restrict__ identity2, uint32* __restrict__ out2, int H) {
    int node = blockIdx.x;
    int c2 = threadIdx.x;            // 0..127
    int C2 = 128 / H;
    int hh = c2 / C2;
    int beg = row_start[node], end = row_start[node + 1];
    float a0 = 0.f, a1 = 0.f;
    for (int idx = beg; idx < end; idx += 4) {
        int   s[4];
        float ww[4];
#pragma unroll
        for (int k = 0; k < 4; ++k) {
            int j = idx + k;
            bool ok = j < end;
            int jj = ok ? j : beg;
            s[k]  = src_sorted[jj];
            ww[k] = ok ? w[(long)jj * H + hh] : 0.f;
        }
#pragma unroll
        for (int k = 0; k < 4; ++k) {
            uint32 u = hbuf2[(long)s[k] * 128 + c2];
            float lo = __uint_as_float(u << 16);
            float hi = __uint_as_float(u & 0xffff0000u);
            a0 += ww[k] * lo;
            a1 += ww[k] * hi;
        }
    }
    int c = 2 * c2;
    float v0 = a0 + bconv[c];
    float v1 = a1 + bconv[c + 1];
    v0 = (v0 - bn_m[c])     * rsqrtf(bn_v[c]     + BN_EPS) * bn_g[c]     + bn_b[c];
    v1 = (v1 - bn_m[c + 1]) * rsqrtf(bn_v[c + 1] + BN_EPS) * bn_g[c + 1] + bn_b[c + 1];
    v0 = (v0 > 0.f) ? v0 : (expf(v0) - 1.f);
    v1 = (v1 > 0.f) ? v1 : (expf(v1) - 1.f);
    uint32 idu = identity2[(long)node * 128 + c2];
    v0 += __uint_as_float(idu << 16);
    v1 += __uint_as_float(idu & 0xffff0000u);
    out2[(long)node * 128 + c2] = pack2(v0, v1);
}

// ---------------------------------------------------------------------------
// pooling (bf16 input; pmax uses monotone-uint atomicMax, init by memset 0)
// ---------------------------------------------------------------------------
#define POOL_ROWS 32
__global__ __launch_bounds__(128) void pool_kernel(
        const uint32* __restrict__ x2, const int* __restrict__ batch,
        float* __restrict__ psum, uint32* __restrict__ pmax, float* __restrict__ pcnt) {
    int c2 = threadIdx.x;
    int n0 = blockIdx.x * POOL_ROWS;
    if (n0 >= Nn) return;
    int n1 = min(n0 + POOL_ROWS, Nn);
    int cur = batch[n0];
    float s0 = 0.f, s1 = 0.f, m0 = -FLT_MAX, m1 = -FLT_MAX;
    int cnt = 0;
    int c = 2 * c2;
    for (int i = n0; i < n1; ++i) {
        int g = batch[i];
        if (g != cur) {
            atomicAdd(&psum[cur * 256 + c], s0);
            atomicAdd(&psum[cur * 256 + c + 1], s1);
            atomicMax(&pmax[cur * 256 + c], fenc(m0));
            atomicMax(&pmax[cur * 256 + c + 1], fenc(m1));
            if (c2 == 0) atomicAdd(&pcnt[cur], (float)cnt);
            cur = g; s0 = s1 = 0.f; m0 = m1 = -FLT_MAX; cnt = 0;
        }
        uint32 u = x2[(long)i * 128 + c2];
        float lo = __uint_as_float(u << 16);
        float hi = __uint_as_float(u & 0xffff0000u);
        s0 += lo; s1 += hi;
        m0 = fmaxf(m0, lo); m1 = fmaxf(m1, hi);
        ++cnt;
    }
    atomicAdd(&psum[cur * 256 + c], s0);
    atomicAdd(&psum[cur * 256 + c + 1], s1);
    atomicMax(&pmax[cur * 256 + c], fenc(m0));
    atomicMax(&pmax[cur * 256 + c + 1], fenc(m1));
    if (c2 == 0) atomicAdd(&pcnt[cur], (float)cnt);
}

// ---------------------------------------------------------------------------
// head MLP: relu(emb @ Wp1 + bp1) @ Wp2 + bp2  -> out[g]
// ---------------------------------------------------------------------------
__global__ __launch_bounds__(256) void mlp_kernel(
        const float* __restrict__ psum, const uint32* __restrict__ pmax,
        const float* __restrict__ pcnt, const float* __restrict__ Wp1,
        const float* __restrict__ bp1, const float* __restrict__ Wp2,
        const float* __restrict__ bp2, float* __restrict__ out) {
    int g = blockIdx.x;
    int j = threadIdx.x;
    float inv = 1.f / fmaxf(pcnt[g], 1.f);
    float acc = bp1[j];
    for (int k = 0; k < 256; ++k)
        acc += (psum[g * 256 + k] * inv) * Wp1[k * 256 + j];
    for (int k = 0; k < 256; ++k)
        acc += fdec(pmax[g * 256 + k]) * Wp1[(256 + k) * 256 + j];
    float v = fmaxf(acc, 0.f) * Wp2[j];
    __shared__ float red[256];
    red[j] = v;
    __syncthreads();
    for (int off = 128; off > 0; off >>= 1) {
        if (j < off) red[j] += red[j + off];
        __syncthreads();
    }
    if (j == 0) out[g] = red[0] + bp2[0];
}

// ---------------------------------------------------------------------------
// launch
// ---------------------------------------------------------------------------
extern "C" void kernel_launch(void* const* d_in, const int* in_sizes, int n_in,
                              void* d_out, int out_size, void* d_ws, size_t ws_size,
                              hipStream_t stream) {
    const float* x   = (const float*)d_in[0];
    const int*   ei  = (const int*)d_in[1];
    const float* ea  = (const float*)d_in[2];
    const int*   bat = (const int*)d_in[3];
    auto LP = [&](int l, int j) { return (const float*)d_in[4 + l * 10 + j]; };
    const float* Wskip = (const float*)d_in[34];
    const float* bskip = (const float*)d_in[35];
    const float* Wp1   = (const float*)d_in[36];
    const float* bp1   = (const float*)d_in[37];
    const float* Wp2   = (const float*)d_in[38];
    const float* bp2   = (const float*)d_in[39];
    float* out = (float*)d_out;

    // workspace carve-up (256B aligned)
    char* p = (char*)d_ws;
    auto alloc = [&](size_t bytes) { void* r = (void*)p; p += (bytes + 255) & ~(size_t)255; return r; };
    uint32*   hbuf2  = (uint32*)alloc((size_t)Nn * 256 * 2);   // bf16 features [n][128] packed
    uint32*   skipbf = (uint32*)alloc((size_t)Nn * 128 * 4);   // bf16 skip residual
    uint32*   resA   = (uint32*)alloc((size_t)Nn * 128 * 4);   // bf16 residual streams
    uint32*   resB   = (uint32*)alloc((size_t)Nn * 128 * 4);
    ushort16* xbf    = (ushort16*)alloc((size_t)Nn * 128 * 2); // bf16 x [n][128]
    float*    wbuf   = (float*)alloc((size_t)Etot * 4 * 4);    // CSR softmax weights
    float*    ea_sorted = (float*)alloc((size_t)Etot * 2 * 4);
    float*    ssrc   = (float*)alloc((size_t)Nn * 4 * 4);      // 4 partial slots
    float*    sdst   = (float*)alloc((size_t)Nn * 4 * 4);
    int*      counts = (int*)alloc((size_t)Nn * 4);
    int*      incb   = (int*)alloc((size_t)Nn * 4);
    int*      row_start = (int*)alloc((size_t)(Nn + 1) * 4);
    int*      cursor    = (int*)alloc((size_t)(Nn + 1) * 4);
    int*      src_sorted = (int*)alloc((size_t)Etot * 4);
    int*      bsums  = (int*)alloc(256 * 4);
    float*    ea_s   = (float*)alloc(2 * 4);
    float*    Mbuf   = (float*)alloc(32 * 4);
    ushort16* WtC    = (ushort16*)alloc((size_t)512 * 128 * 2); // W0 | Wskip swizzled
    ushort16* Wt1    = (ushort16*)alloc((size_t)256 * 256 * 2);
    ushort16* Wt2    = (ushort16*)alloc((size_t)256 * 256 * 2);
    float*    psum   = (float*)alloc((size_t)Gg * 256 * 4);    // psum|pmax|pcnt contiguous
    uint32*   pmax   = (uint32*)alloc((size_t)Gg * 256 * 4);
    float*    pcnt   = (float*)alloc((size_t)Gg * 4);

    const int nb = (Nn + 255) / 256;
    const int wgrid = (Nn * 64 + 255) / 256;

    // zero init
    hipMemsetAsync(counts, 0, (size_t)Nn * 4, stream);
    hipMemsetAsync(ea_s, 0, 8, stream);
    hipMemsetAsync(psum, 0, (size_t)Gg * 256 * 4 * 2 + (size_t)Gg * 4, stream);

    // one prep dispatch: ea_sum + M + W swizzles + x->bf16 + histogram
    prep_kernel<<<1025 + CVT_BLKS + EBKS, 256, 0, stream>>>(
        ea, ea_s, LP(0,3), LP(0,4), LP(1,3), LP(1,4), LP(2,3), LP(2,4), Mbuf,
        LP(0,0), Wskip, LP(1,0), LP(2,0), WtC, Wt1, Wt2, x, xbf, ei, counts);

    // CSR
    scan1_kernel<<<nb, 256, 0, stream>>>(counts, incb, bsums);
    scan23_kernel<<<nb, 256, 0, stream>>>(incb, bsums, row_start, cursor, nb);
    scatter_kernel<<<EBKS, 256, 0, stream>>>(ei, ea, ea_s, cursor, src_sorted, ea_sorted);

    // fused layer-0 GEMM + skip projection + attn dots (K=128, KB=4)
    {
        dim3 g0((Nn + 127) / 128, 4);
        mfma_gemm_kernel<4><<<g0, 256, 0, stream>>>(
            xbf, WtC, hbuf2, skipbf, bskip,
            LP(0,1), LP(0,2), ssrc, sdst, Nn);
    }

    // layers
    const uint32* lid[3] = { skipbf, resA, resB };
    uint32*       lou[3] = { resA, resB, resA };
    const int     Hh[3]  = { 4, 4, 1 };
    const ushort16* lain[3] = { nullptr, (ushort16*)resA, (ushort16*)resB };
    const ushort16* lwt[3]  = { nullptr, Wt1, Wt2 };
    for (int l = 0; l < 3; ++l) {
        const int H = Hh[l];
        if (l > 0) {
            dim3 gl((Nn + 127) / 128, 2);
            mfma_gemm_kernel<8><<<gl, 256, 0, stream>>>(
                lain[l], lwt[l], hbuf2, nullptr, nullptr,
                LP(l,1), LP(l,2), ssrc, sdst, Nn);
        }
        if (H == 4)
            edge_softmax_kernel<4><<<wgrid, 256, 0, stream>>>(
                src_sorted, row_start, ea_sorted, ssrc, sdst, Mbuf + l * 8, wbuf);
        else
            edge_softmax_kernel<1><<<wgrid, 256, 0, stream>>>(
                src_sorted, row_start, ea_sorted, ssrc, sdst, Mbuf + l * 8, wbuf);
        agg_kernel<<<Nn, 128, 0, stream>>>(src_sorted, row_start, hbuf2, wbuf,
            LP(l,5), LP(l,6), LP(l,7), LP(l,8), LP(l,9), lid[l], lou[l], H);
    }

    // pooling + head (final x = resA, bf16-packed)
    pool_kernel<<<(Nn + POOL_ROWS - 1) / POOL_ROWS, 128, 0, stream>>>(resA, bat, psum, pmax, pcnt);
    mlp_kernel<<<Gg, 256, 0, stream>>>(psum, pmax, pcnt, Wp1, bp1, Wp2, bp2, out);
}

// Round 14
// 671.939 us; speedup vs baseline: 1.0773x; 1.0773x over previous
//
#include <hip/hip_runtime.h>
#include <cfloat>

// Problem constants (match reference setup_inputs)
#define Nn 50000
#define Ee 800000
#define Etot (Ee + Nn)   // edges + self loops = 850000
#define Gg 64
#define HIDc 256
#define BN_EPS 1e-5f

typedef unsigned int   uint32;
typedef unsigned short ushort16;
typedef short  bf16x8 __attribute__((ext_vector_type(8)));
typedef float  f32x4  __attribute__((ext_vector_type(4)));

// ---------------------------------------------------------------------------
// helpers
// ---------------------------------------------------------------------------
__device__ inline ushort16 f2bf(float f) {            // RNE fp32 -> bf16
    uint32 u = __float_as_uint(f);
    u = (u + 0x7fffu + ((u >> 16) & 1u)) >> 16;
    return (ushort16)u;
}
__device__ inline uint32 pack2(float a, float b) {
    return (uint32)f2bf(a) | ((uint32)f2bf(b) << 16);
}
// monotone float<->uint encoding for atomicMax-based float max
__device__ inline uint32 fenc(float f) {
    uint32 b = __float_as_uint(f);
    return (b & 0x80000000u) ? ~b : (b | 0x80000000u);
}
__device__ inline float fdec(uint32 u) {
    uint32 b = (u & 0x80000000u) ? (u & 0x7fffffffu) : ~u;
    return __uint_as_float(b);
}

// W swizzle to MFMA A-operand fragment order:
// WS[((cb*KB + kb)*64 + q*16 + m)*8 + e]  where cb=c>>4, m=c&15,
// kb=k>>5, q=(k>>3)&3, e=k&7.  A wave then reads 64 lanes x 16B contiguous.
__device__ inline long ws_index(int c, int k, int KB) {
    int cb = c >> 4, m = c & 15, kb = k >> 5, q = (k >> 3) & 3, e = k & 7;
    return (((long)(cb * KB + kb) * 64 + q * 16 + m) << 3) + e;
}

// ---------------------------------------------------------------------------
// prep kernel: ea_sum | M | W swizzles | x->bf16 | hist   (one dispatch)
// ---------------------------------------------------------------------------
#define CVT4 (Nn * 128 / 4)
#define CVT_BLKS ((CVT4 + 255) / 256)
#define EBKS ((Etot + 255) / 256)
__global__ __launch_bounds__(256) void prep_kernel(
        const float* __restrict__ ea, float* __restrict__ ea_s,
        const float* __restrict__ We0, const float* __restrict__ ae0,
        const float* __restrict__ We1, const float* __restrict__ ae1,
        const float* __restrict__ We2, const float* __restrict__ ae2,
        float* __restrict__ M,
        const float* __restrict__ W0, const float* __restrict__ Wskip,
        const float* __restrict__ W1, const float* __restrict__ W2,
        ushort16* __restrict__ WtC, ushort16* __restrict__ Wt1,
        ushort16* __restrict__ Wt2,
        const float* __restrict__ x, ushort16* __restrict__ xbf,
        const int* __restrict__ ei, int* __restrict__ counts) {
    int bid = blockIdx.x, t = threadIdx.x;
    if (bid < 256) {
        __shared__ float sh0[256], sh1[256];
        float s0 = 0.f, s1 = 0.f;
        for (int e = bid * 256 + t; e < Ee; e += 256 * 256) {
            s0 += ea[2 * e];
            s1 += ea[2 * e + 1];
        }
        sh0[t] = s0; sh1[t] = s1;
        __syncthreads();
        for (int off = 128; off > 0; off >>= 1) {
            if (t < off) { sh0[t] += sh0[t + off]; sh1[t] += sh1[t + off]; }
            __syncthreads();
        }
        if (t == 0) { atomicAdd(&ea_s[0], sh0[0]); atomicAdd(&ea_s[1], sh1[0]); }
    } else if (bid == 256) {
        if (t >= 18) return;
        int l = t < 8 ? 0 : (t < 16 ? 1 : 2);
        int r = t - l * 8;
        const float* We = (l == 0) ? We0 : (l == 1 ? We1 : We2);
        const float* ae = (l == 0) ? ae0 : (l == 1 ? ae1 : ae2);
        int Hl = (l < 2) ? 4 : 1;
        int Cl = 256 / Hl;
        int d = r / Hl, hh = r % Hl;
        float s = 0.f;
        for (int c = 0; c < Cl; ++c)
            s += We[d * 256 + hh * Cl + c] * ae[hh * Cl + c];
        M[l * 8 + r] = s;
    } else if (bid < 385) {          // W0: cols 0..255, K=128 (KB=4)
        int k = bid - 257;
        WtC[ws_index(t, k, 4)] = f2bf(W0[(long)k * 256 + t]);
    } else if (bid < 513) {          // Wskip: cols 256..511, K=128
        int k = bid - 385;
        WtC[ws_index(256 + t, k, 4)] = f2bf(Wskip[(long)k * 256 + t]);
    } else if (bid < 769) {          // W1: K=256 (KB=8)
        int k = bid - 513;
        Wt1[ws_index(t, k, 8)] = f2bf(W1[(long)k * 256 + t]);
    } else if (bid < 1025) {         // W2
        int k = bid - 769;
        Wt2[ws_index(t, k, 8)] = f2bf(W2[(long)k * 256 + t]);
    } else if (bid < 1025 + CVT_BLKS) {
        int i = (bid - 1025) * 256 + t;
        if (i < CVT4) {
            float4 v = *(const float4*)&x[i * 4];
            ushort4 o;
            o.x = f2bf(v.x); o.y = f2bf(v.y); o.z = f2bf(v.z); o.w = f2bf(v.w);
            *(ushort4*)&xbf[i * 4] = o;
        }
    } else {                         // histogram
        int e = (bid - 1025 - CVT_BLKS) * 256 + t;
        if (e < Etot) {
            int d = (e < Ee) ? ei[Ee + e] : (e - Ee);
            atomicAdd(&counts[d], 1);
        }
    }
}

// ---------------------------------------------------------------------------
// CSR build: scan1 -> scan23 -> scatter
// ---------------------------------------------------------------------------
__global__ void scan1_kernel(const int* __restrict__ in, int* __restrict__ inc,
                             int* __restrict__ bsums) {
    __shared__ int sh[256];
    int i = blockIdx.x * 256 + threadIdx.x;
    int v = (i < Nn) ? in[i] : 0;
    sh[threadIdx.x] = v;
    __syncthreads();
    for (int off = 1; off < 256; off <<= 1) {
        int t = ((int)threadIdx.x >= off) ? sh[threadIdx.x - off] : 0;
        __syncthreads();
        sh[threadIdx.x] += t;
        __syncthreads();
    }
    if (i < Nn) inc[i] = sh[threadIdx.x];
    if (threadIdx.x == 255) bsums[blockIdx.x] = sh[255];
}

__global__ void scan23_kernel(const int* __restrict__ inc, const int* __restrict__ bsums,
                              int* __restrict__ row_start, int* __restrict__ cursor, int nb) {
    __shared__ int sh[256];
    int b = blockIdx.x, t = threadIdx.x;
    sh[t] = (t < b && t < nb) ? bsums[t] : 0;
    __syncthreads();
    for (int off = 128; off > 0; off >>= 1) {
        if (t < off) sh[t] += sh[t + off];
        __syncthreads();
    }
    int base = sh[0];
    int i = b * 256 + t;
    if (i < Nn) {
        int v = inc[i] + base;
        row_start[i + 1] = v;
        cursor[i + 1] = v;
    }
    if (i == 0) { row_start[0] = 0; cursor[0] = 0; }
}

__global__ void scatter_kernel(const int* __restrict__ ei, const float* __restrict__ ea,
                               const float* __restrict__ ea_sum, int* __restrict__ cursor,
                               int* __restrict__ src_sorted, float* __restrict__ ea_sorted) {
    int e = blockIdx.x * blockDim.x + threadIdx.x;
    if (e >= Etot) return;
    int s, d; float e0, e1;
    if (e < Ee) {
        s = ei[e]; d = ei[Ee + e];
        e0 = ea[2 * e]; e1 = ea[2 * e + 1];
    } else {
        s = d = e - Ee;
        const float invE = 1.f / (float)Ee;
        e0 = ea_sum[0] * invE; e1 = ea_sum[1] * invE;
    }
    int pos = atomicAdd(&cursor[d], 1);
    src_sorted[pos] = s;
    ea_sorted[2 * pos]     = e0;
    ea_sorted[2 * pos + 1] = e1;
}

// ---------------------------------------------------------------------------
// MFMA bf16 GEMM (R12 config): A staged via LDS (coalesced 1KB loads),
// B read directly from global in fragment-swizzled order (L2-resident).
// Fused attention dots into ssrc/sdst[row*4+part].
// If outS != null: grid.y=4, col blocks 256..511 route to outS (+bskip).
// ---------------------------------------------------------------------------
#define LDK 40
__global__ __launch_bounds__(256) void mfma_gemm_kernel(
        const ushort16* __restrict__ A,   // [n][K] bf16
        const ushort16* __restrict__ WS,  // swizzled weights
        uint32* __restrict__ outF,        // feature out [n][128] packed bf16x2
        uint32* __restrict__ outS,        // skip out (or null)
        const float* __restrict__ bskip,
        const float* __restrict__ a_s, const float* __restrict__ a_d,
        float* __restrict__ ssrc, float* __restrict__ sdst,
        int n, int K) {
    __shared__ ushort16 As[128 * LDK];
    const int t    = threadIdx.x;
    const int row0 = blockIdx.x * 128;
    const int c0   = blockIdx.y * 128;
    const bool isSkip = (outS != nullptr) && (c0 >= 256);
    const int cc0  = isSkip ? c0 - 256 : c0;
    const int wave = t >> 6, lane = t & 63;
    const int wr = wave >> 1, wc = wave & 1;
    const int l15 = lane & 15, quad = lane >> 4;
    const int KB = K >> 5;

    f32x4 acc[4][4];   // acc[j][i]: j = feature-col block, i = node-row block
#pragma unroll
    for (int j = 0; j < 4; ++j)
#pragma unroll
        for (int i = 0; i < 4; ++i) {
            acc[j][i][0] = 0.f; acc[j][i][1] = 0.f;
            acc[j][i][2] = 0.f; acc[j][i][3] = 0.f;
        }

    const int sm = t & 127;
    const int so = t >> 7;

    for (int k0 = 0; k0 < K; k0 += 32) {
        const int kb = k0 >> 5;
#pragma unroll
        for (int h = 0; h < 2; ++h) {
            int oct = so + 2 * h;
            int grow = row0 + sm;
            uint4 va = make_uint4(0, 0, 0, 0);
            if (grow < n) va = *(const uint4*)&A[(long)grow * K + k0 + 8 * oct];
            *(uint4*)&As[sm * LDK + 8 * oct] = va;
        }
        bf16x8 bfv[4];
#pragma unroll
        for (int j = 0; j < 4; ++j) {
            int cb = ((c0 + wc * 64) >> 4) + j;
            bfv[j] = *(const bf16x8*)&WS[(((long)cb * KB + kb) * 64 + lane) << 3];
        }
        __syncthreads();
        bf16x8 af[4];
#pragma unroll
        for (int i = 0; i < 4; ++i)
            af[i] = *(const bf16x8*)&As[(wr * 64 + i * 16 + l15) * LDK + quad * 8];
#pragma unroll
        for (int j = 0; j < 4; ++j)
#pragma unroll
            for (int i = 0; i < 4; ++i)
                acc[j][i] = __builtin_amdgcn_mfma_f32_16x16x32_bf16(
                    bfv[j], af[i], acc[j][i], 0, 0, 0);
        __syncthreads();
    }

    float4 bb[4];
#pragma unroll
    for (int j = 0; j < 4; ++j) {
        if (isSkip) bb[j] = *(const float4*)&bskip[cc0 + wc * 64 + j * 16 + quad * 4];
        else        bb[j] = make_float4(0.f, 0.f, 0.f, 0.f);
    }

    uint32* tgt = isSkip ? outS : outF;
#pragma unroll
    for (int i = 0; i < 4; ++i) {
        int row = row0 + wr * 64 + i * 16 + l15;
        if (row >= n) continue;
#pragma unroll
        for (int j = 0; j < 4; ++j) {
            int col = cc0 + wc * 64 + j * 16 + quad * 4;
            uint2 pk;
            pk.x = pack2(acc[j][i][0] + bb[j].x, acc[j][i][1] + bb[j].y);
            pk.y = pack2(acc[j][i][2] + bb[j].z, acc[j][i][3] + bb[j].w);
            *(uint2*)&tgt[(long)row * 128 + (col >> 1)] = pk;
        }
    }

    if (!isSkip && a_s != nullptr) {
        float4 asv[4], adv[4];
#pragma unroll
        for (int j = 0; j < 4; ++j) {
            int col = cc0 + wc * 64 + j * 16 + quad * 4;
            asv[j] = *(const float4*)&a_s[col];
            adv[j] = *(const float4*)&a_d[col];
        }
        const int part = (cc0 + wc * 64) >> 6;
#pragma unroll
        for (int i = 0; i < 4; ++i) {
            float ps = 0.f, pd = 0.f;
#pragma unroll
            for (int j = 0; j < 4; ++j) {
                ps += acc[j][i][0] * asv[j].x + acc[j][i][1] * asv[j].y
                    + acc[j][i][2] * asv[j].z + acc[j][i][3] * asv[j].w;
                pd += acc[j][i][0] * adv[j].x + acc[j][i][1] * adv[j].y
                    + acc[j][i][2] * adv[j].z + acc[j][i][3] * adv[j].w;
            }
            ps += __shfl_xor(ps, 16); ps += __shfl_xor(ps, 32);
            pd += __shfl_xor(pd, 16); pd += __shfl_xor(pd, 32);
            if (quad == 0) {
                int row = row0 + wr * 64 + i * 16 + l15;
                if (row < n) {
                    ssrc[row * 4 + part] = ps;
                    sdst[row * 4 + part] = pd;
                }
            }
        }
    }
}

// ---------------------------------------------------------------------------
// fused edge logits + segment softmax: 16 LANES PER NODE (4 nodes/wave).
// avg deg = 17, so a full wave/node wasted 73% of lanes; 16-lane groups give
// 4x lane utilization + 4x gather MLP. deg<=64 in registers; butterfly
// shfl_xor(1,2,4,8) stays inside the group. 2-pass global fallback deg>64.
// H==1 sums the 4 partial slots of ssrc/sdst.
// ---------------------------------------------------------------------------
template <int H>
__global__ __launch_bounds__(256) void edge_softmax_kernel(
        const int* __restrict__ src_sorted, const int* __restrict__ row_start,
        const float* __restrict__ ea_sorted, const float* __restrict__ ssrc,
        const float* __restrict__ sdst, const float* __restrict__ M,
        float* __restrict__ w) {
    int node = (blockIdx.x * blockDim.x + threadIdx.x) >> 4;
    int l16 = threadIdx.x & 15;
    if (node >= Nn) return;
    int beg = row_start[node], end = row_start[node + 1];
    int deg = end - beg;
    float sd[H], M0[H], M1[H], m[H], den[H];
    if (H == 4) {
#pragma unroll
        for (int h = 0; h < H; ++h) sd[h] = sdst[node * 4 + h];
    } else {
        float4 v = *(const float4*)&sdst[node * 4];
        sd[0] = v.x + v.y + v.z + v.w;
    }
#pragma unroll
    for (int h = 0; h < H; ++h) {
        M0[h] = M[h]; M1[h] = M[H + h];
        m[h] = -FLT_MAX; den[h] = 0.f;
    }
    auto ssval = [&](int s, int h) -> float {
        if (H == 4) return ssrc[s * 4 + h];
        float4 v = *(const float4*)&ssrc[s * 4];
        return v.x + v.y + v.z + v.w;
    };
    if (deg <= 64) {
        float lreg[4][H];
#pragma unroll
        for (int k = 0; k < 4; ++k) {
            int idx = beg + l16 + (k << 4);
            if (idx < end) {
                int s = src_sorted[idx];
                float e0 = ea_sorted[2 * idx], e1 = ea_sorted[2 * idx + 1];
#pragma unroll
                for (int h = 0; h < H; ++h) {
                    float l = ssval(s, h) + sd[h] + e0 * M0[h] + e1 * M1[h];
                    l = (l > 0.f) ? l : 0.2f * l;
                    lreg[k][h] = l;
                    if (l > m[h]) { den[h] = den[h] * __expf(m[h] - l) + 1.f; m[h] = l; }
                    else den[h] += __expf(l - m[h]);
                }
            }
        }
        // butterfly combine within the 16-lane group (all lanes converge)
#pragma unroll
        for (int h = 0; h < H; ++h) {
#pragma unroll
            for (int off = 1; off < 16; off <<= 1) {
                float om = __shfl_xor(m[h], off);
                float od = __shfl_xor(den[h], off);
                float nm = fmaxf(m[h], om);
                den[h] = den[h] * __expf(m[h] - nm) + od * __expf(om - nm);
                m[h] = nm;
            }
            den[h] = 1.f / (den[h] + 1e-16f);
        }
#pragma unroll
        for (int k = 0; k < 4; ++k) {
            int idx = beg + l16 + (k << 4);
            if (idx < end) {
#pragma unroll
                for (int h = 0; h < H; ++h)
                    w[(long)idx * H + h] = __expf(lreg[k][h] - m[h]) * den[h];
            }
        }
    } else {
        // 2-pass fallback (16-lane strided)
        for (int idx = beg + l16; idx < end; idx += 16) {
            int s = src_sorted[idx];
            float e0 = ea_sorted[2 * idx], e1 = ea_sorted[2 * idx + 1];
#pragma unroll
            for (int h = 0; h < H; ++h) {
                float l = ssval(s, h) + sd[h] + e0 * M0[h] + e1 * M1[h];
                l = (l > 0.f) ? l : 0.2f * l;
                w[(long)idx * H + h] = l;
                if (l > m[h]) { den[h] = den[h] * __expf(m[h] - l) + 1.f; m[h] = l; }
                else den[h] += __expf(l - m[h]);
            }
        }
#pragma unroll
        for (int h = 0; h < H; ++h) {
#pragma unroll
            for (int off = 1; off < 16; off <<= 1) {
                float om = __shfl_xor(m[h], off);
                float od = __shfl_xor(den[h], off);
                float nm = fmaxf(m[h], om);
                den[h] = den[h] * __expf(m[h] - nm) + od * __expf(om - nm);
                m[h] = nm;
            }
            den[h] = 1.f / (den[h] + 1e-16f);
        }
        for (int idx = beg + l16; idx < end; idx += 16) {
#pragma unroll
            for (int h = 0; h < H; ++h) {
                float l = w[(long)idx * H + h];
                w[(long)idx * H + h] = __expf(l - m[h]) * den[h];
            }
        }
    }
}

// ---------------------------------------------------------------------------
// weighted gather (bf16 features) + bconv + BN + ELU + residual(bf16).
// 128 threads/node; thread c2 handles channels 2c2,2c2+1 (packed bf16x2).
// ---------------------------------------------------------------------------
__global__ __launch_bounds__(128) void agg_kernel(
        const int* __restrict__ src_sorted, const int* __restrict__ row_start,
        const uint32* __restrict__ hbuf2, const float* __restrict__ w,
        const float* __restrict__ bconv,
        const float* __restrict__ bn_g, const float* __restrict__ bn_b,
        const float* __restrict__ bn_m, const float* __restrict__ bn_v,
        const uint32* __restrict__ identity2, uint32* __restrict__ out2, int H) {
    int node = blockIdx.x;
    int c2 = threadIdx.x;            // 0..127
    int C2 = 128 / H;
    int hh = c2 / C2;
    int beg = row_start[node], end = row_start[node + 1];
    float a0 = 0.f, a1 = 0.f;
    for (int idx = beg; idx < end; idx += 4) {
        int   s[4];
        float ww[4];
#pragma unroll
        for (int k = 0; k < 4; ++k) {
            int j = idx + k;
            bool ok = j < end;
            int jj = ok ? j : beg;
            s[k]  = src_sorted[jj];
            ww[k] = ok ? w[(long)jj * H + hh] : 0.f;
        }
#pragma unroll
        for (int k = 0; k < 4; ++k) {
            uint32 u = hbuf2[(long)s[k] * 128 + c2];
            float lo = __uint_as_float(u << 16);
            float hi = __uint_as_float(u & 0xffff0000u);
            a0 += ww[k] * lo;
            a1 += ww[k] * hi;
        }
    }
    int c = 2 * c2;
    float v0 = a0 + bconv[c];
    float v1 = a1 + bconv[c + 1];
    v0 = (v0 - bn_m[c])     * rsqrtf(bn_v[c]     + BN_EPS) * bn_g[c]     + bn_b[c];
    v1 = (v1 - bn_m[c + 1]) * rsqrtf(bn_v[c + 1] + BN_EPS) * bn_g[c + 1] + bn_b[c + 1];
    v0 = (v0 > 0.f) ? v0 : (expf(v0) - 1.f);
    v1 = (v1 > 0.f) ? v1 : (expf(v1) - 1.f);
    uint32 idu = identity2[(long)node * 128 + c2];
    v0 += __uint_as_float(idu << 16);
    v1 += __uint_as_float(idu & 0xffff0000u);
    out2[(long)node * 128 + c2] = pack2(v0, v1);
}

// ---------------------------------------------------------------------------
// pooling (bf16 input; pmax uses monotone-uint atomicMax, init by memset 0)
// ---------------------------------------------------------------------------
#define POOL_ROWS 32
__global__ __launch_bounds__(128) void pool_kernel(
        const uint32* __restrict__ x2, const int* __restrict__ batch,
        float* __restrict__ psum, uint32* __restrict__ pmax, float* __restrict__ pcnt) {
    int c2 = threadIdx.x;
    int n0 = blockIdx.x * POOL_ROWS;
    if (n0 >= Nn) return;
    int n1 = min(n0 + POOL_ROWS, Nn);
    int cur = batch[n0];
    float s0 = 0.f, s1 = 0.f, m0 = -FLT_MAX, m1 = -FLT_MAX;
    int cnt = 0;
    int c = 2 * c2;
    for (int i = n0; i < n1; ++i) {
        int g = batch[i];
        if (g != cur) {
            atomicAdd(&psum[cur * 256 + c], s0);
            atomicAdd(&psum[cur * 256 + c + 1], s1);
            atomicMax(&pmax[cur * 256 + c], fenc(m0));
            atomicMax(&pmax[cur * 256 + c + 1], fenc(m1));
            if (c2 == 0) atomicAdd(&pcnt[cur], (float)cnt);
            cur = g; s0 = s1 = 0.f; m0 = m1 = -FLT_MAX; cnt = 0;
        }
        uint32 u = x2[(long)i * 128 + c2];
        float lo = __uint_as_float(u << 16);
        float hi = __uint_as_float(u & 0xffff0000u);
        s0 += lo; s1 += hi;
        m0 = fmaxf(m0, lo); m1 = fmaxf(m1, hi);
        ++cnt;
    }
    atomicAdd(&psum[cur * 256 + c], s0);
    atomicAdd(&psum[cur * 256 + c + 1], s1);
    atomicMax(&pmax[cur * 256 + c], fenc(m0));
    atomicMax(&pmax[cur * 256 + c + 1], fenc(m1));
    if (c2 == 0) atomicAdd(&pcnt[cur], (float)cnt);
}

// ---------------------------------------------------------------------------
// head MLP: relu(emb @ Wp1 + bp1) @ Wp2 + bp2  -> out[g]
// ---------------------------------------------------------------------------
__global__ __launch_bounds__(256) void mlp_kernel(
        const float* __restrict__ psum, const uint32* __restrict__ pmax,
        const float* __restrict__ pcnt, const float* __restrict__ Wp1,
        const float* __restrict__ bp1, const float* __restrict__ Wp2,
        const float* __restrict__ bp2, float* __restrict__ out) {
    int g = blockIdx.x;
    int j = threadIdx.x;
    float inv = 1.f / fmaxf(pcnt[g], 1.f);
    float acc = bp1[j];
    for (int k = 0; k < 256; ++k)
        acc += (psum[g * 256 + k] * inv) * Wp1[k * 256 + j];
    for (int k = 0; k < 256; ++k)
        acc += fdec(pmax[g * 256 + k]) * Wp1[(256 + k) * 256 + j];
    float v = fmaxf(acc, 0.f) * Wp2[j];
    __shared__ float red[256];
    red[j] = v;
    __syncthreads();
    for (int off = 128; off > 0; off >>= 1) {
        if (j < off) red[j] += red[j + off];
        __syncthreads();
    }
    if (j == 0) out[g] = red[0] + bp2[0];
}

// ---------------------------------------------------------------------------
// launch
// ---------------------------------------------------------------------------
extern "C" void kernel_launch(void* const* d_in, const int* in_sizes, int n_in,
                              void* d_out, int out_size, void* d_ws, size_t ws_size,
                              hipStream_t stream) {
    const float* x   = (const float*)d_in[0];
    const int*   ei  = (const int*)d_in[1];
    const float* ea  = (const float*)d_in[2];
    const int*   bat = (const int*)d_in[3];
    auto LP = [&](int l, int j) { return (const float*)d_in[4 + l * 10 + j]; };
    const float* Wskip = (const float*)d_in[34];
    const float* bskip = (const float*)d_in[35];
    const float* Wp1   = (const float*)d_in[36];
    const float* bp1   = (const float*)d_in[37];
    const float* Wp2   = (const float*)d_in[38];
    const float* bp2   = (const float*)d_in[39];
    float* out = (float*)d_out;

    // workspace carve-up (256B aligned)
    char* p = (char*)d_ws;
    auto alloc = [&](size_t bytes) { void* r = (void*)p; p += (bytes + 255) & ~(size_t)255; return r; };
    uint32*   hbuf2  = (uint32*)alloc((size_t)Nn * 256 * 2);   // bf16 features [n][128] packed
    uint32*   skipbf = (uint32*)alloc((size_t)Nn * 128 * 4);   // bf16 skip residual
    uint32*   resA   = (uint32*)alloc((size_t)Nn * 128 * 4);   // bf16 residual streams
    uint32*   resB   = (uint32*)alloc((size_t)Nn * 128 * 4);
    ushort16* xbf    = (ushort16*)alloc((size_t)Nn * 128 * 2); // bf16 x [n][128]
    float*    wbuf   = (float*)alloc((size_t)Etot * 4 * 4);    // CSR softmax weights
    float*    ea_sorted = (float*)alloc((size_t)Etot * 2 * 4);
    float*    ssrc   = (float*)alloc((size_t)Nn * 4 * 4);      // 4 partial slots
    float*    sdst   = (float*)alloc((size_t)Nn * 4 * 4);
    int*      counts = (int*)alloc((size_t)Nn * 4);
    int*      incb   = (int*)alloc((size_t)Nn * 4);
    int*      row_start = (int*)alloc((size_t)(Nn + 1) * 4);
    int*      cursor    = (int*)alloc((size_t)(Nn + 1) * 4);
    int*      src_sorted = (int*)alloc((size_t)Etot * 4);
    int*      bsums  = (int*)alloc(256 * 4);
    float*    ea_s   = (float*)alloc(2 * 4);
    float*    Mbuf   = (float*)alloc(32 * 4);
    ushort16* WtC    = (ushort16*)alloc((size_t)512 * 128 * 2); // W0 | Wskip swizzled
    ushort16* Wt1    = (ushort16*)alloc((size_t)256 * 256 * 2);
    ushort16* Wt2    = (ushort16*)alloc((size_t)256 * 256 * 2);
    float*    psum   = (float*)alloc((size_t)Gg * 256 * 4);    // psum|pmax|pcnt contiguous
    uint32*   pmax   = (uint32*)alloc((size_t)Gg * 256 * 4);
    float*    pcnt   = (float*)alloc((size_t)Gg * 4);

    const int nb = (Nn + 255) / 256;
    const int sgrid = (Nn * 16 + 255) / 256;   // 16-lane-group softmax

    // zero init
    hipMemsetAsync(counts, 0, (size_t)Nn * 4, stream);
    hipMemsetAsync(ea_s, 0, 8, stream);
    hipMemsetAsync(psum, 0, (size_t)Gg * 256 * 4 * 2 + (size_t)Gg * 4, stream);

    // one prep dispatch: ea_sum + M + W swizzles + x->bf16 + histogram
    prep_kernel<<<1025 + CVT_BLKS + EBKS, 256, 0, stream>>>(
        ea, ea_s, LP(0,3), LP(0,4), LP(1,3), LP(1,4), LP(2,3), LP(2,4), Mbuf,
        LP(0,0), Wskip, LP(1,0), LP(2,0), WtC, Wt1, Wt2, x, xbf, ei, counts);

    // CSR
    scan1_kernel<<<nb, 256, 0, stream>>>(counts, incb, bsums);
    scan23_kernel<<<nb, 256, 0, stream>>>(incb, bsums, row_start, cursor, nb);
    scatter_kernel<<<EBKS, 256, 0, stream>>>(ei, ea, ea_s, cursor, src_sorted, ea_sorted);

    // fused layer-0 GEMM + skip projection + attn dots (K=128)
    {
        dim3 g0((Nn + 127) / 128, 4);
        mfma_gemm_kernel<<<g0, 256, 0, stream>>>(
            xbf, WtC, hbuf2, skipbf, bskip,
            LP(0,1), LP(0,2), ssrc, sdst, Nn, 128);
    }

    // layers
    const uint32* lid[3] = { skipbf, resA, resB };
    uint32*       lou[3] = { resA, resB, resA };
    const int     Hh[3]  = { 4, 4, 1 };
    const ushort16* lain[3] = { nullptr, (ushort16*)resA, (ushort16*)resB };
    const ushort16* lwt[3]  = { nullptr, Wt1, Wt2 };
    for (int l = 0; l < 3; ++l) {
        const int H = Hh[l];
        if (l > 0) {
            dim3 gl((Nn + 127) / 128, 2);
            mfma_gemm_kernel<<<gl, 256, 0, stream>>>(
                lain[l], lwt[l], hbuf2, nullptr, nullptr,
                LP(l,1), LP(l,2), ssrc, sdst, Nn, 256);
        }
        if (H == 4)
            edge_softmax_kernel<4><<<sgrid, 256, 0, stream>>>(
                src_sorted, row_start, ea_sorted, ssrc, sdst, Mbuf + l * 8, wbuf);
        else
            edge_softmax_kernel<1><<<sgrid, 256, 0, stream>>>(
                src_sorted, row_start, ea_sorted, ssrc, sdst, Mbuf + l * 8, wbuf);
        agg_kernel<<<Nn, 128, 0, stream>>>(src_sorted, row_start, hbuf2, wbuf,
            LP(l,5), LP(l,6), LP(l,7), LP(l,8), LP(l,9), lid[l], lou[l], H);
    }

    // pooling + head (final x = resA, bf16-packed)
    pool_kernel<<<(Nn + POOL_ROWS - 1) / POOL_ROWS, 128, 0, stream>>>(resA, bat, psum, pmax, pcnt);
    mlp_kernel<<<Gg, 256, 0, stream>>>(psum, pmax, pcnt, Wp1, bp1, Wp2, bp2, out);
}